// Round 6
// baseline (2060.046 us; speedup 1.0000x reference)
//
#include <hip/hip_runtime.h>
#include <stdint.h>

#define N_SITES 144
#define NHID    256
#define NSAMP   1024
#define MB      4          // samples per block
#define TPB     768        // 12 waves: 2 sample-groups x 384 col-threads (C=2)
#define NCOL    768

__device__ __forceinline__ uint32_t rotl32(uint32_t v, uint32_t r) {
    return (v << r) | (v >> (32u - r));
}

// JAX threefry2x32: 20 rounds, key injections every 4
__device__ __forceinline__ void threefry(uint32_t k0, uint32_t k1,
                                         uint32_t x0, uint32_t x1,
                                         uint32_t& o0, uint32_t& o1) {
    uint32_t ks0 = k0, ks1 = k1, ks2 = k0 ^ k1 ^ 0x1BD11BDAu;
    x0 += ks0; x1 += ks1;
#define RG4(a,b,c,d) \
    x0 += x1; x1 = rotl32(x1,a); x1 ^= x0; \
    x0 += x1; x1 = rotl32(x1,b); x1 ^= x0; \
    x0 += x1; x1 = rotl32(x1,c); x1 ^= x0; \
    x0 += x1; x1 = rotl32(x1,d); x1 ^= x0;
    RG4(13,15,26,6)  x0 += ks1; x1 += ks2 + 1u;
    RG4(17,29,16,24) x0 += ks2; x1 += ks0 + 2u;
    RG4(13,15,26,6)  x0 += ks0; x1 += ks1 + 3u;
    RG4(17,29,16,24) x0 += ks1; x1 += ks2 + 4u;
    RG4(13,15,26,6)  x0 += ks2; x1 += ks0 + 5u;
#undef RG4
    o0 = x0; o1 = x1;
}

__device__ __forceinline__ float gumbel_from_bits(uint32_t bits) {
#pragma clang fp contract(off)
    const float TINY = 1.17549435e-38f;          // finfo(f32).tiny
    uint32_t fb = (bits >> 9) | 0x3f800000u;
    float u = __uint_as_float(fb) - 1.0f;        // [0,1)
    u = u * (1.0f - TINY) + TINY;                // matches JAX uniform()
    u = fmaxf(TINY, u);
    return -logf(-logf(u));
}

__global__ __launch_bounds__(TPB, 1)
void rnn_sample_kernel(const float* __restrict__ kern,   // [2,768]
                       const float* __restrict__ rec,    // [256,768]
                       const float* __restrict__ bias,   // [2,768]
                       const float* __restrict__ dw,     // [256,2]
                       const float* __restrict__ db,     // [2]
                       float* __restrict__ out)          // samples[1024*144] ++ logP[1024]
{
    const int t    = threadIdx.x;
    const int blk  = blockIdx.x;
    const int b0   = blk * MB;
    const int lane = t & 63;

    // phase A mapping: sample-group sg (2 samples) x column pair {tc, tc+384}
    const int sg = t / 384;                // 0: samples 0,1   1: samples 2,3
    const int tc = t - sg * 384;

    // phase B/C mapping (threads 0..511): unit u, sample-pair mg
    const int u  = t & 255;
    const int mg = (t >> 8) & 1;
    const int wv = t >> 6;                 // 0..7 for t<512

    __shared__ float4   hs4[NHID];          // h[k] packed over 4 samples (4 KB)
    __shared__ float    pacc[MB][NCOL];     // phase-A partials (12 KB)
    __shared__ uint32_t keyA[N_SITES], keyB[N_SITES];
    __shared__ float    wred[8][4];         // [wave][2*mm+c], wave = mg*4 + u-chunk
    __shared__ int      sPrev[MB];
    __shared__ float    lgP[MB];

    // ---- per-unit constants (used by threads 0..511; u = t&255) ----
    const float kz0 = kern[u],       kr0 = kern[u + 256],       kn0 = kern[u + 512];
    const float kz1 = kern[768 + u], kr1 = kern[768 + u + 256], kn1 = kern[768 + u + 512];
    const float b0z = bias[u],       b0r = bias[u + 256],       b0n = bias[u + 512];
    const float b1z = bias[768 + u], b1r = bias[768 + u + 256], b1n = bias[768 + u + 512];
    const float dwa = dw[2 * u], dwb = dw[2 * u + 1];
    const float dba = db[0],     dbb = db[1];

    if (t < NHID) hs4[t] = make_float4(0.f, 0.f, 0.f, 0.f);
    if (t < MB) { sPrev[t] = -1; lgP[t] = 0.f; }
    if (t < N_SITES) {
        uint32_t o0, o1;
        threefry(0u, 42u, 0u, (uint32_t)t, o0, o1);   // foldlike split: counter = n
        keyA[t] = o0; keyB[t] = o1;
    }
    __syncthreads();

    const float2* h2p = (const float2*)hs4;   // h2p[2k+sg] = samples {2sg,2sg+1} of h[k]

    for (int n = 0; n < N_SITES; ++n) {
        // ---- phase A: 2 samples x 2 cols per thread; ds_read_b64 per k (8 B).
        //      Each (m,c) accumulator is a full sequential k-chain -> bit-exact. ----
        float b00 = 0.f, b01 = 0.f, b10 = 0.f, b11 = 0.f;  // [m0|m1][c0|c1]
        {
            const float* rp = rec + tc;
#pragma unroll 8
            for (int k = 0; k < NHID; ++k) {
                float2 hv = h2p[2 * k + sg];   // broadcast ds_read_b64
                float w0 = rp[0];
                float w1 = rp[384];
                rp += NCOL;
                b00 = fmaf(hv.x, w0, b00);
                b10 = fmaf(hv.y, w0, b10);
                b01 = fmaf(hv.x, w1, b01);
                b11 = fmaf(hv.y, w1, b11);
            }
        }
        {
            const int m0 = 2 * sg, m1 = 2 * sg + 1;
            pacc[m0][tc]       = b00;
            pacc[m0][tc + 384] = b01;
            pacc[m1][tc]       = b10;
            pacc[m1][tc + 384] = b11;
        }
        __syncthreads();   // B1: pacc + sPrev (from prev step's D) published

        // ---- phases B+C: threads 0..511, one (unit u, sample-pair mg) each ----
        float hnew[2];
        if (t < 512) {
            float2 ho = ((const float2*)&hs4[u])[mg];
            float hold[2] = { ho.x, ho.y };
            {
#pragma clang fp contract(off)
#pragma unroll
                for (int mm = 0; mm < 2; ++mm) {
                    const int sp = sPrev[2 * mg + mm];
                    float xz = (sp == 0) ? kz0 : ((sp == 1) ? kz1 : 0.f);
                    float xr = (sp == 0) ? kr0 : ((sp == 1) ? kr1 : 0.f);
                    float xh = (sp == 0) ? kn0 : ((sp == 1) ? kn1 : 0.f);
                    xz = xz + b0z;  xr = xr + b0r;  xh = xh + b0n;
                    const float hz = pacc[2 * mg + mm][u]       + b1z;
                    const float hr = pacc[2 * mg + mm][u + 256] + b1r;
                    const float hn = pacc[2 * mg + mm][u + 512] + b1n;
                    const float z = 1.0f / (1.0f + expf(-(xz + hz)));
                    const float r = 1.0f / (1.0f + expf(-(xr + hr)));
                    const float rhn = r * hn;
                    const float hh = tanhf(xh + rhn);
                    hnew[mm] = z * hold[mm] + (1.0f - z) * hh;
                }
            }
            ((float2*)&hs4[u])[mg] = make_float2(hnew[0], hnew[1]);

            // dense partials: wave wv covers u-chunk (wv&3) of sample-pair mg;
            // shfl tree identical to verified kernel
#pragma unroll
            for (int mm = 0; mm < 2; ++mm) {
                float va = hnew[mm] * dwa;
                float vb = hnew[mm] * dwb;
#pragma unroll
                for (int off = 32; off > 0; off >>= 1) {
                    va += __shfl_xor(va, off, 64);
                    vb += __shfl_xor(vb, off, 64);
                }
                if (lane == 0) { wred[wv][2 * mm] = va; wred[wv][2 * mm + 1] = vb; }
            }
        }
        __syncthreads();   // B2: wred + hs4(new) published

        // ---- phase D: 4 threads; overlaps next step's phase A (no barrier) ----
        if (t < MB) {
            const int m = t;
            const int g = (m >> 1) * 4;     // wave base for this sample's pair
            const int mm = m & 1;
            // u-chunk-ascending order, identical to verified summation
            float l0 = wred[g + 0][2 * mm] + wred[g + 1][2 * mm]
                     + wred[g + 2][2 * mm] + wred[g + 3][2 * mm];
            float l1 = wred[g + 0][2 * mm + 1] + wred[g + 1][2 * mm + 1]
                     + wred[g + 2][2 * mm + 1] + wred[g + 3][2 * mm + 1];
            uint32_t o0a, o1a, o0b, o1b;
            const uint32_t fbase = 2u * (uint32_t)(b0 + m);
            threefry(keyA[n], keyB[n], 0u, fbase,      o0a, o1a);
            threefry(keyA[n], keyB[n], 0u, fbase + 1u, o0b, o1b);
            const float g0 = gumbel_from_bits(o0a ^ o1a);
            const float g1 = gumbel_from_bits(o0b ^ o1b);
            {
#pragma clang fp contract(off)
                l0 = l0 + dba;
                l1 = l1 + dbb;
                const float mx = fmaxf(l0, l1);
                const float e0 = expf(l0 - mx), e1 = expf(l1 - mx);
                const float den = e0 + e1;
                const float lp0 = logf(1e-10f + e0 / den);
                const float lp1 = logf(1e-10f + e1 / den);
                const float v0 = g0 + lp0;
                const float v1 = g1 + lp1;
                const int s = (v1 > v0) ? 1 : 0;   // argmax, first-index tie-break
                sPrev[m] = s;
                lgP[m] = lgP[m] + (s ? lp1 : lp0);
                out[(size_t)(b0 + m) * N_SITES + n] = (float)s;
            }
        }
        // no trailing barrier: next A reads hs4 (stable since B2), writes pacc
        // (WAR-safe: B's pacc reads done before B2); sPrev consumed after next B1.
    }

    __syncthreads();
    if (t < MB) out[(size_t)NSAMP * N_SITES + (b0 + t)] = lgP[t];
}

extern "C" void kernel_launch(void* const* d_in, const int* in_sizes, int n_in,
                              void* d_out, int out_size, void* d_ws, size_t ws_size,
                              hipStream_t stream) {
    (void)in_sizes; (void)n_in; (void)d_ws; (void)ws_size; (void)out_size;
    const float* kern = (const float*)d_in[0];
    const float* rec  = (const float*)d_in[1];
    const float* bias = (const float*)d_in[2];
    const float* dwp  = (const float*)d_in[3];
    const float* dbp  = (const float*)d_in[4];
    float* out = (float*)d_out;
    rnn_sample_kernel<<<NSAMP / MB, TPB, 0, stream>>>(kern, rec, bias, dwp, dbp, out);
}